// Round 4
// baseline (224.890 us; speedup 1.0000x reference)
//
#include <hip/hip_runtime.h>
#include <hip/hip_bf16.h>

// Bilinear edge scoring:  out[e] = x_source[src[e]] @ W @ x_target[tgt[e]] + b
// Factored: Zb = bf16(x_source @ W) via bf16 MFMA GEMM (fp32 accum),
//           XTb = bf16(x_target),
//           out[e] = dot(Zb[src[e]], XTb[tgt[e]]) + b  (fp32 accum).
// Edge phase is gather-miss-bound -> counting-sort edges by src>>6 so the
// src stream becomes L1-resident per chunk; XCD-chunked block mapping keeps
// each sorted range on one XCD's L2.

#define D 128
#define NBMAX 2048          // max src buckets (N<=131072, bucket=64 nodes)
#define CHUNK 4096          // edges per scatter block

typedef short bf16x8 __attribute__((ext_vector_type(8)));
typedef float f32x4 __attribute__((ext_vector_type(4)));
typedef unsigned int uint;

__device__ __forceinline__ unsigned short f2bf_rn(float f) {
    uint u = __float_as_uint(f);
    u += 0x7fff + ((u >> 16) & 1);
    return (unsigned short)(u >> 16);
}
__device__ __forceinline__ uint pack2bf(float a, float b) {
    return (uint)f2bf_rn(a) | ((uint)f2bf_rn(b) << 16);
}
__device__ __forceinline__ float bdot8(uint4 za, uint4 xa) {
    float p;
    p  = __uint_as_float(za.x << 16) * __uint_as_float(xa.x << 16);
    p += __uint_as_float(za.x & 0xffff0000u) * __uint_as_float(xa.x & 0xffff0000u);
    p += __uint_as_float(za.y << 16) * __uint_as_float(xa.y << 16);
    p += __uint_as_float(za.y & 0xffff0000u) * __uint_as_float(xa.y & 0xffff0000u);
    p += __uint_as_float(za.z << 16) * __uint_as_float(xa.z << 16);
    p += __uint_as_float(za.z & 0xffff0000u) * __uint_as_float(xa.z & 0xffff0000u);
    p += __uint_as_float(za.w << 16) * __uint_as_float(xa.w << 16);
    p += __uint_as_float(za.w & 0xffff0000u) * __uint_as_float(xa.w & 0xffff0000u);
    return p;
}

// ---------------------------------------------------------------------------
// Wtb[n][k] = bf16(W[k][n])
// ---------------------------------------------------------------------------
__global__ __launch_bounds__(256) void wt_cast(const float* __restrict__ W,
                                               unsigned short* __restrict__ Wtb) {
    int idx = blockIdx.x * 256 + threadIdx.x;
    int k = idx >> 7, n = idx & 127;
    Wtb[n * 128 + k] = f2bf_rn(W[idx]);
}

// ---------------------------------------------------------------------------
// Zb = bf16(X @ W) via mfma_f32_16x16x32_bf16 (unchanged from round 3; passed).
// ---------------------------------------------------------------------------
__global__ __launch_bounds__(256) void gemm_xw_mfma(const float* __restrict__ X,
                                                    const unsigned short* __restrict__ Wtb,
                                                    unsigned short* __restrict__ Zb, int N) {
    __shared__ unsigned short wls[128 * 128];
    __shared__ unsigned short xls[64 * 128];

    const int tid = threadIdx.x;
    const int block_row = blockIdx.x * 64;

#pragma unroll
    for (int j = 0; j < 8; ++j) {
        int c16 = j * 256 + tid;
        int row = c16 >> 4;
        int kb = (c16 & 15) << 4;
        uint4 v = ((const uint4*)Wtb)[c16];
        *(uint4*)((char*)wls + row * 256 + (kb ^ ((row & 7) << 4))) = v;
    }
#pragma unroll
    for (int j = 0; j < 4; ++j) {
        int c16 = j * 256 + tid;
        int row = c16 >> 4;
        int kb = (c16 & 15) << 4;
        int grow = block_row + row;
        float4 f0 = make_float4(0.f, 0.f, 0.f, 0.f), f1 = f0;
        if (grow < N) {
            const float4* src = (const float4*)(X + (size_t)grow * D + (kb >> 1));
            f0 = src[0];
            f1 = src[1];
        }
        uint4 v;
        v.x = pack2bf(f0.x, f0.y);
        v.y = pack2bf(f0.z, f0.w);
        v.z = pack2bf(f1.x, f1.y);
        v.w = pack2bf(f1.z, f1.w);
        *(uint4*)((char*)xls + row * 256 + (kb ^ ((row & 7) << 4))) = v;
    }
    __syncthreads();

    const int lane = tid & 63;
    const int w = tid >> 6;
    const int lr = lane & 15;
    const int kg = lane >> 4;

    f32x4 acc[8];
#pragma unroll
    for (int nb = 0; nb < 8; ++nb) acc[nb] = (f32x4){0.f, 0.f, 0.f, 0.f};

    const int arow = w * 16 + lr;
    const int swz = (lr & 7) << 4;
#pragma unroll
    for (int ks = 0; ks < 4; ++ks) {
        int kbyte = ks * 64 + kg * 16;
        bf16x8 a = *(const bf16x8*)((const char*)xls + arow * 256 + (kbyte ^ swz));
#pragma unroll
        for (int nb = 0; nb < 8; ++nb) {
            int nrow = nb * 16 + lr;
            bf16x8 b = *(const bf16x8*)((const char*)wls + nrow * 256 + (kbyte ^ swz));
            acc[nb] = __builtin_amdgcn_mfma_f32_16x16x32_bf16(a, b, acc[nb], 0, 0, 0);
        }
    }

    const int orow0 = block_row + w * 16 + kg * 4;
#pragma unroll
    for (int nb = 0; nb < 8; ++nb) {
        int col = nb * 16 + lr;
#pragma unroll
        for (int j = 0; j < 4; ++j) {
            int grow = orow0 + j;
            if (grow < N) Zb[(size_t)grow * D + col] = f2bf_rn(acc[nb][j]);
        }
    }
}

// ---------------------------------------------------------------------------
// streaming fp32 -> bf16 cast
// ---------------------------------------------------------------------------
__global__ __launch_bounds__(256) void cast_to_bf16(const float* __restrict__ in,
                                                    unsigned short* __restrict__ outb,
                                                    int n8) {
    int i = blockIdx.x * blockDim.x + threadIdx.x;
    const int stride = gridDim.x * blockDim.x;
    for (; i < n8; i += stride) {
        float4 a = ((const float4*)in)[2 * i];
        float4 c = ((const float4*)in)[2 * i + 1];
        uint4 o;
        o.x = pack2bf(a.x, a.y);
        o.y = pack2bf(a.z, a.w);
        o.z = pack2bf(c.x, c.y);
        o.w = pack2bf(c.z, c.w);
        ((uint4*)outb)[i] = o;
    }
}

// ---------------------------------------------------------------------------
// Sort pass A: global histogram of src>>6
// ---------------------------------------------------------------------------
__global__ __launch_bounds__(256) void hist_kernel(const int* __restrict__ idx,
                                                   uint* __restrict__ gbase,
                                                   int E, int NB) {
    __shared__ uint h[NBMAX];
    for (int j = threadIdx.x; j < NB; j += 256) h[j] = 0;
    __syncthreads();
    int i = blockIdx.x * 256 + threadIdx.x;
    const int stride = gridDim.x * 256;
    for (; i < E; i += stride) atomicAdd(&h[((uint)idx[i]) >> 6], 1u);
    __syncthreads();
    for (int j = threadIdx.x; j < NB; j += 256) {
        uint c = h[j];
        if (c) atomicAdd(&gbase[j], c);
    }
}

// ---------------------------------------------------------------------------
// Sort pass B: in-place exclusive scan of gbase[0..NB) (single block)
// ---------------------------------------------------------------------------
__global__ __launch_bounds__(256) void scan_kernel(uint* __restrict__ gbase, int NB) {
    __shared__ uint part[256];
    const int tid = threadIdx.x;
    const int per = (NB + 255) / 256;
    uint loc[8];
    uint s = 0;
    int base = tid * per;
#pragma unroll
    for (int k = 0; k < 8; ++k) {
        uint v = (k < per && base + k < NB) ? gbase[base + k] : 0;
        loc[k] = v;
        s += v;
    }
    part[tid] = s;
    __syncthreads();
    for (int off = 1; off < 256; off <<= 1) {
        uint v = (tid >= off) ? part[tid - off] : 0;
        __syncthreads();
        part[tid] += v;
        __syncthreads();
    }
    uint run = part[tid] - s;      // exclusive prefix of this thread's span
#pragma unroll
    for (int k = 0; k < 8; ++k) {
        if (k < per && base + k < NB) {
            gbase[base + k] = run;
            run += loc[k];
        }
    }
}

// ---------------------------------------------------------------------------
// Sort pass C: LDS-aggregated scatter into packed records
// rec.x = src | (tgt<<17)   rec.y = (tgt>>15) | (e<<2)
// ---------------------------------------------------------------------------
__global__ __launch_bounds__(256) void scatter_kernel(const int* __restrict__ idx,
                                                      uint* __restrict__ gbase,
                                                      uint2* __restrict__ recs,
                                                      int E, int NB) {
    __shared__ uint lsrc[CHUNK];
    __shared__ uint ltgt[CHUNK];
    __shared__ uint lh[NBMAX];
    const int tid = threadIdx.x;
    const int base_e = blockIdx.x * CHUNK;
    const int cnt = min(CHUNK, E - base_e);

    for (int j = tid; j < cnt; j += 256) {
        lsrc[j] = (uint)idx[base_e + j];
        ltgt[j] = (uint)idx[E + base_e + j];
    }
    for (int j = tid; j < NB; j += 256) lh[j] = 0;
    __syncthreads();
    for (int j = tid; j < cnt; j += 256) atomicAdd(&lh[lsrc[j] >> 6], 1u);
    __syncthreads();
    for (int j = tid; j < NB; j += 256) {
        uint c = lh[j];
        if (c) lh[j] = atomicAdd(&gbase[j], c);   // reserve range; lh := base
    }
    __syncthreads();
    for (int j = tid; j < cnt; j += 256) {
        uint s = lsrc[j], t = ltgt[j];
        uint e = (uint)(base_e + j);
        uint pos = atomicAdd(&lh[s >> 6], 1u);
        uint2 r;
        r.x = s | (t << 17);
        r.y = (t >> 15) | (e << 2);
        recs[pos] = r;
    }
}

// ---------------------------------------------------------------------------
// Compute pass over sorted records. XCD-chunked: block bid -> chunk
// (bid&7)*(nblk/8) + bid>>3 so each XCD owns a contiguous sorted range.
// 16 lanes/edge, 4 edges/wave.
// ---------------------------------------------------------------------------
__global__ __launch_bounds__(256) void sorted_edge_score(const unsigned short* __restrict__ Zb,
                                                         const unsigned short* __restrict__ XTb,
                                                         const uint2* __restrict__ recs,
                                                         const float* __restrict__ bptr,
                                                         float* __restrict__ out,
                                                         int E, int nblk) {
    const float b = bptr[0];
    const int per = (E + nblk - 1) / nblk;
    const int cb = (int)((blockIdx.x & 7) * (nblk >> 3) + (blockIdx.x >> 3));
    const int start = cb * per;
    const int end = min(start + per, E);
    const int tid = threadIdx.x;
    const int wv = tid >> 6;
    const int lane = tid & 63;
    const int sub = lane >> 4;
    const int l = lane & 15;

    for (int base = start; base < end; base += 16) {
        int r = base + wv * 4 + sub;
        float p = 0.f;
        uint e = 0;
        bool valid = (r < end);
        if (valid) {
            uint2 rec = recs[r];
            uint s = rec.x & 0x1FFFFu;
            uint t = ((rec.x >> 17) | (rec.y << 15)) & 0x1FFFFu;
            e = rec.y >> 2;
            uint4 za = ((const uint4*)(Zb + (size_t)s * D))[l];
            uint4 xa = ((const uint4*)(XTb + (size_t)t * D))[l];
            p = bdot8(za, xa);
        }
        p += __shfl_xor(p, 1, 64);
        p += __shfl_xor(p, 2, 64);
        p += __shfl_xor(p, 4, 64);
        p += __shfl_xor(p, 8, 64);
        if (l == 0 && valid) out[e] = p + b;
    }
}

// ---------------------------------------------------------------------------
// Fallback: direct (unsorted) edge pass — round-2 structure, no NT hints.
// ---------------------------------------------------------------------------
__global__ __launch_bounds__(256) void edge_score(const unsigned short* __restrict__ Zb,
                                                  const unsigned short* __restrict__ XTb,
                                                  const int* __restrict__ idx,
                                                  const float* __restrict__ bptr,
                                                  float* __restrict__ out, int E) {
    const float b = bptr[0];
    const int lane = threadIdx.x & 63;
    const int sub = lane >> 4;
    const int l = lane & 15;
    const int waveGlobal = blockIdx.x * 4 + (threadIdx.x >> 6);
    const int totalWaves = gridDim.x * 4;
    const int nQuads = (E + 3) >> 2;

    for (int w = waveGlobal; w < nQuads; w += totalWaves) {
        int e = w * 4 + sub;
        float p = 0.f;
        bool valid = (e < E);
        if (valid) {
            int s = idx[e];
            int t = idx[E + e];
            uint4 za = ((const uint4*)(Zb + (size_t)s * D))[l];
            uint4 xa = ((const uint4*)(XTb + (size_t)t * D))[l];
            p = bdot8(za, xa);
        }
        p += __shfl_xor(p, 1, 64);
        p += __shfl_xor(p, 2, 64);
        p += __shfl_xor(p, 4, 64);
        p += __shfl_xor(p, 8, 64);
        if (l == 0 && valid) out[e] = p + b;
    }
}

extern "C" void kernel_launch(void* const* d_in, const int* in_sizes, int n_in,
                              void* d_out, int out_size, void* d_ws, size_t ws_size,
                              hipStream_t stream) {
    const float* x_source = (const float*)d_in[0];
    const float* x_target = (const float*)d_in[1];
    const int* edge_idx = (const int*)d_in[2];
    const float* W = (const float*)d_in[3];
    const float* b = (const float*)d_in[4];
    float* out = (float*)d_out;

    const int N = in_sizes[0] / D;           // 100000
    const int E = in_sizes[2] / 2;           // 2000000
    const int NB = (N + 63) >> 6;            // src buckets (64 nodes each)

    const size_t zb_bytes = (size_t)N * D * 2;
    unsigned short* Zb = (unsigned short*)d_ws;
    unsigned short* XTb = (unsigned short*)((char*)d_ws + zb_bytes);
    unsigned short* Wtb = (unsigned short*)((char*)d_ws + 2 * zb_bytes);
    size_t gbase_off = (2 * zb_bytes + (size_t)128 * 128 * 2 + 255) & ~(size_t)255;
    uint* gbase = (uint*)((char*)d_ws + gbase_off);
    size_t recs_off = (gbase_off + (size_t)NB * 4 + 255) & ~(size_t)255;
    uint2* recs = (uint2*)((char*)d_ws + recs_off);
    const size_t need = recs_off + (size_t)E * 8;

    const bool sorted_ok = (N <= (1 << 17)) && (E < (1 << 21)) &&
                           (NB <= NBMAX) && (need <= ws_size);

    wt_cast<<<64, 256, 0, stream>>>(W, Wtb);
    cast_to_bf16<<<2048, 256, 0, stream>>>(x_target, XTb, N * D / 8);
    gemm_xw_mfma<<<(N + 63) / 64, 256, 0, stream>>>(x_source, Wtb, Zb, N);

    if (sorted_ok) {
        hipMemsetAsync(gbase, 0, (size_t)NB * 4, stream);
        hist_kernel<<<512, 256, 0, stream>>>(edge_idx, gbase, E, NB);
        scan_kernel<<<1, 256, 0, stream>>>(gbase, NB);
        scatter_kernel<<<(E + CHUNK - 1) / CHUNK, 256, 0, stream>>>(edge_idx, gbase, recs, E, NB);
        sorted_edge_score<<<2048, 256, 0, stream>>>(Zb, XTb, recs, b, out, E, 2048);
    } else {
        edge_score<<<2048, 256, 0, stream>>>(Zb, XTb, edge_idx, b, out, E);
    }
}

// Round 5
// 173.708 us; speedup vs baseline: 1.2946x; 1.2946x over previous
//
#include <hip/hip_runtime.h>
#include <hip/hip_bf16.h>

// Bilinear edge scoring:  out[e] = x_source[src[e]] @ W @ x_target[tgt[e]] + b
// Factored: Zb = bf16(x_source @ W) via bf16 MFMA GEMM (fp32 accum),
//           XTb = bf16(x_target),
//           out[e] = dot(Zb[src[e]], XTb[tgt[e]]) + b  (fp32 accum).
// Round-4 lesson: edge-sorting's locality gain (<110 MB) is eaten by the
// permutation's write-allocate amplification — sort reverted. Edge phase runs
// at (FETCH+WRITE)/3.6 TB/s; this round tests whether that rate is a BW wall
// or an MLP limit by issuing 4x the in-flight gathers per wave.

#define D 128

typedef short bf16x8 __attribute__((ext_vector_type(8)));
typedef float f32x4 __attribute__((ext_vector_type(4)));
typedef unsigned int uint;

__device__ __forceinline__ unsigned short f2bf_rn(float f) {
    uint u = __float_as_uint(f);
    u += 0x7fff + ((u >> 16) & 1);          // round-to-nearest-even
    return (unsigned short)(u >> 16);
}
__device__ __forceinline__ uint pack2bf(float a, float b) {
    return (uint)f2bf_rn(a) | ((uint)f2bf_rn(b) << 16);
}
__device__ __forceinline__ float bdot8(uint4 za, uint4 xa) {
    float p;
    p  = __uint_as_float(za.x << 16) * __uint_as_float(xa.x << 16);
    p += __uint_as_float(za.x & 0xffff0000u) * __uint_as_float(xa.x & 0xffff0000u);
    p += __uint_as_float(za.y << 16) * __uint_as_float(xa.y << 16);
    p += __uint_as_float(za.y & 0xffff0000u) * __uint_as_float(xa.y & 0xffff0000u);
    p += __uint_as_float(za.z << 16) * __uint_as_float(xa.z << 16);
    p += __uint_as_float(za.z & 0xffff0000u) * __uint_as_float(xa.z & 0xffff0000u);
    p += __uint_as_float(za.w << 16) * __uint_as_float(xa.w << 16);
    p += __uint_as_float(za.w & 0xffff0000u) * __uint_as_float(xa.w & 0xffff0000u);
    return p;
}

// ---------------------------------------------------------------------------
// Wtb[n][k] = bf16(W[k][n])   (one-time 128x128 transpose+cast)
// ---------------------------------------------------------------------------
__global__ __launch_bounds__(256) void wt_cast(const float* __restrict__ W,
                                               unsigned short* __restrict__ Wtb) {
    int idx = blockIdx.x * 256 + threadIdx.x;
    int k = idx >> 7, n = idx & 127;
    Wtb[n * 128 + k] = f2bf_rn(W[idx]);
}

// ---------------------------------------------------------------------------
// Zb = bf16(X @ W) via mfma_f32_16x16x32_bf16 (verified rounds 3-4).
// LDS XOR-swizzle byte^=(row&7)<<4 breaks the 256B-stride bank conflict.
// ---------------------------------------------------------------------------
__global__ __launch_bounds__(256) void gemm_xw_mfma(const float* __restrict__ X,
                                                    const unsigned short* __restrict__ Wtb,
                                                    unsigned short* __restrict__ Zb, int N) {
    __shared__ unsigned short wls[128 * 128];
    __shared__ unsigned short xls[64 * 128];

    const int tid = threadIdx.x;
    const int block_row = blockIdx.x * 64;

#pragma unroll
    for (int j = 0; j < 8; ++j) {
        int c16 = j * 256 + tid;
        int row = c16 >> 4;
        int kb = (c16 & 15) << 4;
        uint4 v = ((const uint4*)Wtb)[c16];
        *(uint4*)((char*)wls + row * 256 + (kb ^ ((row & 7) << 4))) = v;
    }
#pragma unroll
    for (int j = 0; j < 4; ++j) {
        int c16 = j * 256 + tid;
        int row = c16 >> 4;
        int kb = (c16 & 15) << 4;
        int grow = block_row + row;
        float4 f0 = make_float4(0.f, 0.f, 0.f, 0.f), f1 = f0;
        if (grow < N) {
            const float4* src = (const float4*)(X + (size_t)grow * D + (kb >> 1));
            f0 = src[0];
            f1 = src[1];
        }
        uint4 v;
        v.x = pack2bf(f0.x, f0.y);
        v.y = pack2bf(f0.z, f0.w);
        v.z = pack2bf(f1.x, f1.y);
        v.w = pack2bf(f1.z, f1.w);
        *(uint4*)((char*)xls + row * 256 + (kb ^ ((row & 7) << 4))) = v;
    }
    __syncthreads();

    const int lane = tid & 63;
    const int w = tid >> 6;
    const int lr = lane & 15;
    const int kg = lane >> 4;

    f32x4 acc[8];
#pragma unroll
    for (int nb = 0; nb < 8; ++nb) acc[nb] = (f32x4){0.f, 0.f, 0.f, 0.f};

    const int arow = w * 16 + lr;
    const int swz = (lr & 7) << 4;
#pragma unroll
    for (int ks = 0; ks < 4; ++ks) {
        int kbyte = ks * 64 + kg * 16;
        bf16x8 a = *(const bf16x8*)((const char*)xls + arow * 256 + (kbyte ^ swz));
#pragma unroll
        for (int nb = 0; nb < 8; ++nb) {
            int nrow = nb * 16 + lr;
            bf16x8 b = *(const bf16x8*)((const char*)wls + nrow * 256 + (kbyte ^ swz));
            acc[nb] = __builtin_amdgcn_mfma_f32_16x16x32_bf16(a, b, acc[nb], 0, 0, 0);
        }
    }

    const int orow0 = block_row + w * 16 + kg * 4;
#pragma unroll
    for (int nb = 0; nb < 8; ++nb) {
        int col = nb * 16 + lr;
#pragma unroll
        for (int j = 0; j < 4; ++j) {
            int grow = orow0 + j;
            if (grow < N) Zb[(size_t)grow * D + col] = f2bf_rn(acc[nb][j]);
        }
    }
}

// ---------------------------------------------------------------------------
// streaming fp32 -> bf16 cast
// ---------------------------------------------------------------------------
__global__ __launch_bounds__(256) void cast_to_bf16(const float* __restrict__ in,
                                                    unsigned short* __restrict__ outb,
                                                    int n8) {
    int i = blockIdx.x * blockDim.x + threadIdx.x;
    const int stride = gridDim.x * blockDim.x;
    for (; i < n8; i += stride) {
        float4 a = ((const float4*)in)[2 * i];
        float4 c = ((const float4*)in)[2 * i + 1];
        uint4 o;
        o.x = pack2bf(a.x, a.y);
        o.y = pack2bf(a.z, a.w);
        o.z = pack2bf(c.x, c.y);
        o.w = pack2bf(c.z, c.w);
        ((uint4*)outb)[i] = o;
    }
}

// ---------------------------------------------------------------------------
// Edge pass, 4x unrolled for MLP: 16 lanes/edge, 16 edges per wave-iteration,
// all 8 row-gathers issued before any reduction. Plain loads (no NT hints).
// ---------------------------------------------------------------------------
__global__ __launch_bounds__(256) void edge_score(const unsigned short* __restrict__ Zb,
                                                  const unsigned short* __restrict__ XTb,
                                                  const int* __restrict__ idx,
                                                  const float* __restrict__ bptr,
                                                  float* __restrict__ out, int E) {
    const float b = bptr[0];
    const int lane = threadIdx.x & 63;
    const int sub = lane >> 4;          // 0..3
    const int l = lane & 15;
    const int waveGlobal = blockIdx.x * 4 + (threadIdx.x >> 6);
    const int totalWaves = gridDim.x * 4;
    const int nGroups = (E + 15) >> 4;  // 16 edges per group

    for (int g = waveGlobal; g < nGroups; g += totalWaves) {
        const int e0 = g * 16 + sub;        // edges e0, e0+4, e0+8, e0+12
        int s[4], t[4];
        bool v[4];
#pragma unroll
        for (int u = 0; u < 4; ++u) {
            int e = e0 + u * 4;
            v[u] = (e < E);
            s[u] = v[u] ? idx[e] : 0;
            t[u] = v[u] ? idx[E + e] : 0;
        }
        // issue all 8 gathers before any arithmetic
        uint4 za[4], xa[4];
#pragma unroll
        for (int u = 0; u < 4; ++u) {
            za[u] = ((const uint4*)(Zb + (size_t)s[u] * D))[l];
            xa[u] = ((const uint4*)(XTb + (size_t)t[u] * D))[l];
        }
        float p[4];
#pragma unroll
        for (int u = 0; u < 4; ++u) {
            float q = bdot8(za[u], xa[u]);
            q += __shfl_xor(q, 1, 64);
            q += __shfl_xor(q, 2, 64);
            q += __shfl_xor(q, 4, 64);
            q += __shfl_xor(q, 8, 64);
            p[u] = q;
        }
        if (l == 0) {
#pragma unroll
            for (int u = 0; u < 4; ++u) {
                int e = e0 + u * 4;
                if (v[u]) out[e] = p[u] + b;
            }
        }
    }
}

extern "C" void kernel_launch(void* const* d_in, const int* in_sizes, int n_in,
                              void* d_out, int out_size, void* d_ws, size_t ws_size,
                              hipStream_t stream) {
    const float* x_source = (const float*)d_in[0];
    const float* x_target = (const float*)d_in[1];
    const int* edge_idx = (const int*)d_in[2];
    const float* W = (const float*)d_in[3];
    const float* b = (const float*)d_in[4];
    float* out = (float*)d_out;

    const int N = in_sizes[0] / D;           // 100000
    const int E = in_sizes[2] / 2;           // 2000000

    unsigned short* Zb = (unsigned short*)d_ws;          // [N,128] bf16
    unsigned short* XTb = Zb + (size_t)N * D;            // [N,128] bf16
    unsigned short* Wtb = XTb + (size_t)N * D;           // [128,128] bf16

    wt_cast<<<64, 256, 0, stream>>>(W, Wtb);
    cast_to_bf16<<<2048, 256, 0, stream>>>(x_target, XTb, N * D / 8);
    gemm_xw_mfma<<<(N + 63) / 64, 256, 0, stream>>>(x_source, Wtb, Zb, N);
    edge_score<<<2048, 256, 0, stream>>>(Zb, XTb, edge_idx, b, out, E);
}